// Round 17
// baseline (66.160 us; speedup 1.0000x reference)
//
#include <hip/hip_runtime.h>
#include <hip/hip_bf16.h>

// Sizes (fixed by the problem)
#define NS   4096      // samples
#define NV   256       // variables/channels
#define NHID 64        // hidden
#define K2F  2.8853900817779268f   // 2*log2(e)

typedef short s8v __attribute__((ext_vector_type(8)));
typedef float f4v __attribute__((ext_vector_type(4)));

typedef __attribute__((address_space(1))) const unsigned int GU;
typedef __attribute__((address_space(3))) unsigned int LU;

__device__ __forceinline__ void gload16(const void* gp, void* lp) {
    __builtin_amdgcn_global_load_lds((GU*)gp, (LU*)lp, 16, 0, 0);
}

__device__ __forceinline__ unsigned short f2bf(float x) {
    __hip_bfloat16 h = __float2bfloat16(x);
    return *reinterpret_cast<unsigned short*>(&h);
}

// ---- merged prep: blocks [0,1024): W2t ; [1024,2192): data/out0/g2/BO/bi2 ----
// W2t[col][k] = adj[k,c] * w_in[c, k-(k>c), h],  col = c*64+h
__global__ __launch_bounds__(256) void k_prep_all(
        const float* __restrict__ adj, const float* __restrict__ w_in,
        unsigned short* __restrict__ W2t,
        const float* __restrict__ data, unsigned short* __restrict__ dataB,
        float* __restrict__ out0,
        const float* __restrict__ neurons, const float* __restrict__ w_out,
        const float* __restrict__ b_out, float* __restrict__ g2, float* __restrict__ BO,
        const float* __restrict__ b_in, float* __restrict__ bi2)
{
    __shared__ float t[64][65];
    const int blk = blockIdx.x, tid = threadIdx.x;
    if (blk < 1024) {
        int c  = blk >> 2;
        int k0 = (blk & 3) * 64;
#pragma unroll
        for (int i = 0; i < 16; ++i) {
            int lin = i * 256 + tid;
            int kr = lin >> 6, h = lin & 63;
            int k = k0 + kr;
            float v = 0.0f;
            if (k != c) {
                int m = k - (k > c ? 1 : 0);
                v = adj[k * NV + c] * w_in[((size_t)c * 255 + m) * 64 + h];
            }
            t[kr][h] = v;
        }
        __syncthreads();
#pragma unroll
        for (int i = 0; i < 16; ++i) {
            int lin = i * 256 + tid;
            int h = lin >> 6, kr = lin & 63;
            W2t[((size_t)(c * 64 + h)) * NV + k0 + kr] = f2bf(t[kr][h]);
        }
        return;
    }
    const int b = blk - 1024;
    if (b < 1024) {                       // data f32 -> bf16 (262144 float4)
        int i = b * 256 + tid;
        float4 v = reinterpret_cast<const float4*>(data)[i];
        ushort4 o = make_ushort4(f2bf(v.x), f2bf(v.y), f2bf(v.z), f2bf(v.w));
        reinterpret_cast<ushort4*>(dataB)[i] = o;
    } else if (b < 1088) {                // out0 = adj (16384 float4)
        int i = (b - 1024) * 256 + tid;
        reinterpret_cast<float4*>(out0)[i] = reinterpret_cast<const float4*>(adj)[i];
    } else if (b < 1152) {                // g2[j]=2*neurons[h,c]*w_out[j]; BO[c]=b_out[c]+sum_h g
        int j = (b - 1088) * 256 + tid;
        int c = j >> 6, h = j & 63;
        float gv = neurons[h * NV + c] * w_out[j];
        g2[j] = 2.0f * gv;
        float s = gv;
        s += __shfl_xor(s, 1);  s += __shfl_xor(s, 2);  s += __shfl_xor(s, 4);
        s += __shfl_xor(s, 8);  s += __shfl_xor(s, 16); s += __shfl_xor(s, 32);
        if ((tid & 63) == 0) BO[c] = b_out[c] + s;
    } else {                              // bi2 = K2 * b_in (4096 float4)
        int i = (b - 1152) * 256 + tid;
        float4 v = reinterpret_cast<const float4*>(b_in)[i];
        v.x *= K2F; v.y *= K2F; v.z *= K2F; v.w *= K2F;
        reinterpret_cast<float4*>(bi2)[i] = v;
    }
}

// ---- main: PRODUCER/CONSUMER wave specialization. 512 threads = 8 waves:
// w0-3 consumers (each 64m x 128n = 2 channels, acc[4][8]), w4-7 producers.
// Tile 128x256, BK=64, K=4 tiles, 3-buffer LDS ring (3 x 48KB = 144KB dyn).
// Producers: stage tile via global_load_lds, vmcnt(0), barrier -- they absorb
// ALL memory latency. Consumers: barrier -> ds_read+MFMA, never touch vmcnt.
// Ring audit: stage(k+2)->buf[(k+2)%3] issued only after B_k (consumers done
// reading that buf); tile k+1 drained before B_{k+1}. 3 barriers both paths.
// Fragment/swizzle/MFMA/epilogue byte-identical to R8/R16-verified path.
__global__ __launch_bounds__(512, 2) void k_gemm_fused(
        const unsigned short* __restrict__ dataB,   // [4096][256] bf16
        const unsigned short* __restrict__ W2t,     // [16384][256] bf16
        const float* __restrict__ g2,               // [16384] 2*g
        const float* __restrict__ bi2,              // [16384] K2*b_in
        const float* __restrict__ BO,               // [256]  b_out + sum_h g
        float* __restrict__ out1)                   // [4096][256]
{
    extern __shared__ __align__(16) char lds[];     // 3 x (A 16K | B 32K)
    const int tid  = threadIdx.x;
    const int w    = tid >> 6;
    const int lane = tid & 63;
    const int lq   = lane >> 4, lr = lane & 15;

    // Bijective XCD swizzle: 2048 = 8 XCD x 256 (32 m x 8 n per XCD -> 3MB/L2)
    const int orig = (int)blockIdx.x;
    const int swz  = (orig & 7) * 256 + (orig >> 3);
    const int bm0  = (swz & 31) << 7;               // m-strip * 128
    const int bn0  = (swz >> 5) << 8;               // n-group * 256

    if (w >= 4) {
        // ---------------- producers (waves 4-7) ----------------
        const int ptid = tid - 256;
        const int pw   = ptid >> 6;
        unsigned offA[4], ldsoA[4], offB[8], ldsoB[8];
#pragma unroll
        for (int t = 0; t < 4; ++t) {
            int o = pw * 4096 + t * 1024 + lane * 16;
            int row = o >> 7;
            int inner = (o & 127) ^ ((row & 7) << 4);   // inverse swz on source
            ldsoA[t] = (unsigned)(pw * 4096 + t * 1024); // wave-uniform base
            offA[t]  = (unsigned)(bm0 + row) * 512u + (unsigned)inner;
        }
#pragma unroll
        for (int t = 0; t < 8; ++t) {
            int o = pw * 8192 + t * 1024 + lane * 16;
            int row = o >> 7;
            int inner = (o & 127) ^ ((row & 7) << 4);
            ldsoB[t] = (unsigned)(16384 + pw * 8192 + t * 1024);
            offB[t]  = (unsigned)(bn0 + row) * 512u + (unsigned)inner;
        }
        const char* dA = (const char*)dataB;
        const char* dB = (const char*)W2t;

#define STAGE(KT, BUFO)                                                        \
        do {                                                                   \
            _Pragma("unroll")                                                  \
            for (int t = 0; t < 4; ++t)                                        \
                gload16(dA + (size_t)offA[t] + (KT) * 128, lds + (BUFO) + ldsoA[t]); \
            _Pragma("unroll")                                                  \
            for (int t = 0; t < 8; ++t)                                        \
                gload16(dB + (size_t)offB[t] + (KT) * 128, lds + (BUFO) + ldsoB[t]); \
        } while (0)

        STAGE(0, 0);
        STAGE(1, 49152);
        asm volatile("s_waitcnt vmcnt(12)" ::: "memory");   // tile0 landed
        __builtin_amdgcn_s_barrier();                       // B0
        STAGE(2, 98304);
        asm volatile("s_waitcnt vmcnt(0)" ::: "memory");    // tiles 1,2 landed
        __builtin_amdgcn_s_barrier();                       // B1
        STAGE(3, 0);                                        // buf0 freed at B1
        asm volatile("s_waitcnt vmcnt(0)" ::: "memory");    // tile3 landed
        __builtin_amdgcn_s_barrier();                       // B2
#undef STAGE
        return;
    }

    // ---------------- consumers (waves 0-3) ----------------
    const int wr = w >> 1, wc = w & 1;

    f4v acc[4][8];
#pragma unroll
    for (int mi = 0; mi < 4; ++mi)
#pragma unroll
        for (int ni = 0; ni < 8; ++ni)
            acc[mi][ni] = (f4v){0.f, 0.f, 0.f, 0.f};

#define COMPUTE(BUFO)                                                          \
    do {                                                                       \
        _Pragma("unroll")                                                      \
        for (int kk = 0; kk < 2; ++kk) {                                       \
            s8v afr[4], bfr[8];                                                \
            _Pragma("unroll")                                                  \
            for (int mi = 0; mi < 4; ++mi) {                                   \
                int ml = wr * 64 + mi * 16 + lr;                               \
                int inner = (kk * 64 + (lq << 4)) ^ ((ml & 7) << 4);           \
                afr[mi] = *reinterpret_cast<const s8v*>(lds + (BUFO) + ml * 128 + inner); \
            }                                                                  \
            _Pragma("unroll")                                                  \
            for (int ni = 0; ni < 8; ++ni) {                                   \
                int nl = wc * 128 + ni * 16 + lr;                              \
                int inner = (kk * 64 + (lq << 4)) ^ ((nl & 7) << 4);           \
                bfr[ni] = *reinterpret_cast<const s8v*>(lds + (BUFO) + 16384 + nl * 128 + inner); \
            }                                                                  \
            __builtin_amdgcn_s_setprio(1);                                     \
            _Pragma("unroll")                                                  \
            for (int mi = 0; mi < 4; ++mi) {                                   \
                _Pragma("unroll")                                              \
                for (int ni = 0; ni < 8; ++ni)                                 \
                    acc[mi][ni] = __builtin_amdgcn_mfma_f32_16x16x32_bf16(     \
                        bfr[ni], afr[mi], acc[mi][ni], 0, 0, 0);               \
            }                                                                  \
            __builtin_amdgcn_s_setprio(0);                                     \
        }                                                                      \
    } while (0)

    __builtin_amdgcn_s_barrier();       // B0: tile0 ready
    COMPUTE(0);
    __builtin_amdgcn_s_barrier();       // B1: tile1 ready (tile2 also landed)
    COMPUTE(49152);
    __builtin_amdgcn_s_barrier();       // B2: tile3 ready (staged into buf0)
    COMPUTE(98304);
    COMPUTE(0);                         // tile3 in buf0; no hazard, no barrier
#undef COMPUTE

    // Epilogue (R8-validated layout): lane holds D[h = (ni&3)*16+lq*4+j][m = lr]
    // for channel = wc*2 + (ni>>2).  out[m,c] = BO[c] - sum_h g2*rcp(1+exp2(.))
#define EPI_TERM(T, GC, BC, RR)                                                \
    { float mm = __builtin_fmaf(acc[mi][nb + ni][RR], K2F, (BC));              \
      float e  = __builtin_amdgcn_exp2f(mm);                                   \
      (T) = __builtin_fmaf((GC), __builtin_amdgcn_rcpf(e + 1.0f), (T)); }
#define EPI_MI(T, MI)                                                          \
    { const int mi = (MI); float t = 0.f;                                      \
      _Pragma("unroll")                                                        \
      for (int ni = 0; ni < 4; ++ni) {                                         \
          EPI_TERM(t, g2v[ni].x, bi2v[ni].x, 0);                               \
          EPI_TERM(t, g2v[ni].y, bi2v[ni].y, 1);                               \
          EPI_TERM(t, g2v[ni].z, bi2v[ni].z, 2);                               \
          EPI_TERM(t, g2v[ni].w, bi2v[ni].w, 3);                               \
      }                                                                        \
      t += __shfl_xor(t, 16);                                                  \
      t += __shfl_xor(t, 32);                                                  \
      (T) = t; }

#pragma unroll
    for (int ch = 0; ch < 2; ++ch) {
        const int nb   = ch * 4;
        const int cidx = (bn0 >> 6) + wc * 2 + ch;
        float4 g2v[4], bi2v[4];
#pragma unroll
        for (int ni = 0; ni < 4; ++ni) {
            int base = cidx * 64 + ni * 16 + lq * 4;
            g2v[ni]  = *(const float4*)&g2 [base];
            bi2v[ni] = *(const float4*)&bi2[base];
        }
        const float BOv = BO[cidx];
        float s0, s1, s2, s3;
        EPI_MI(s0, 0); EPI_MI(s1, 1); EPI_MI(s2, 2); EPI_MI(s3, 3);
        float v = lane < 16 ? s0 : (lane < 32 ? s1 : (lane < 48 ? s2 : s3));
        out1[(unsigned)(bm0 + wr * 64 + lane) * NV + cidx] = BOv - v;
    }
#undef EPI_MI
#undef EPI_TERM
}

extern "C" void kernel_launch(void* const* d_in, const int* in_sizes, int n_in,
                              void* d_out, int out_size, void* d_ws, size_t ws_size,
                              hipStream_t stream) {
    const float* data    = (const float*)d_in[0];
    const float* adj     = (const float*)d_in[1];
    const float* neurons = (const float*)d_in[2];
    const float* w_in    = (const float*)d_in[3];
    const float* b_in    = (const float*)d_in[4];
    const float* w_out   = (const float*)d_in[5];
    const float* b_out   = (const float*)d_in[6];

    float* out0 = (float*)d_out;
    float* out1 = out0 + NV * NV;

    unsigned short* dataB = (unsigned short*)d_ws;                       // 2 MiB
    unsigned short* W2t   = (unsigned short*)((char*)d_ws + 2097152);    // 8 MiB
    float*          g2    = (float*)((char*)d_ws + 10485760);            // 64 KiB
    float*          bi2   = (float*)((char*)d_ws + 10551296);            // 64 KiB
    float*          BO    = (float*)((char*)d_ws + 10616832);            // 1 KiB

    hipLaunchKernelGGL(k_prep_all, dim3(2192), dim3(256), 0, stream,
                       adj, w_in, W2t, data, dataB, out0,
                       neurons, w_out, b_out, g2, BO, b_in, bi2);
    hipLaunchKernelGGL(k_gemm_fused, dim3(2048), dim3(512), 147456, stream,
                       dataB, W2t, g2, bi2, BO, out1);
}

// Round 18
// 64.808 us; speedup vs baseline: 1.0209x; 1.0209x over previous
//
#include <hip/hip_runtime.h>
#include <hip/hip_bf16.h>

// Sizes (fixed by the problem)
#define NS   4096      // samples
#define NV   256       // variables/channels
#define NHID 64        // hidden
#define K2F  2.8853900817779268f   // 2*log2(e)

typedef short s8v __attribute__((ext_vector_type(8)));
typedef float f16v __attribute__((ext_vector_type(16)));

typedef __attribute__((address_space(1))) const unsigned int GU;
typedef __attribute__((address_space(3))) unsigned int LU;

__device__ __forceinline__ void gload16(const void* gp, void* lp) {
    __builtin_amdgcn_global_load_lds((GU*)gp, (LU*)lp, 16, 0, 0);
}

__device__ __forceinline__ unsigned short f2bf(float x) {
    __hip_bfloat16 h = __float2bfloat16(x);
    return *reinterpret_cast<unsigned short*>(&h);
}

// ---- merged prep: blocks [0,1024): W2t ; [1024,2192): data/out0/g2/BO/bi2 ----
// W2t[col][k] = adj[k,c] * w_in[c, k-(k>c), h],  col = c*64+h
__global__ __launch_bounds__(256) void k_prep_all(
        const float* __restrict__ adj, const float* __restrict__ w_in,
        unsigned short* __restrict__ W2t,
        const float* __restrict__ data, unsigned short* __restrict__ dataB,
        float* __restrict__ out0,
        const float* __restrict__ neurons, const float* __restrict__ w_out,
        const float* __restrict__ b_out, float* __restrict__ g2, float* __restrict__ BO,
        const float* __restrict__ b_in, float* __restrict__ bi2)
{
    __shared__ float t[64][65];
    const int blk = blockIdx.x, tid = threadIdx.x;
    if (blk < 1024) {
        int c  = blk >> 2;
        int k0 = (blk & 3) * 64;
#pragma unroll
        for (int i = 0; i < 16; ++i) {
            int lin = i * 256 + tid;
            int kr = lin >> 6, h = lin & 63;
            int k = k0 + kr;
            float v = 0.0f;
            if (k != c) {
                int m = k - (k > c ? 1 : 0);
                v = adj[k * NV + c] * w_in[((size_t)c * 255 + m) * 64 + h];
            }
            t[kr][h] = v;
        }
        __syncthreads();
#pragma unroll
        for (int i = 0; i < 16; ++i) {
            int lin = i * 256 + tid;
            int h = lin >> 6, kr = lin & 63;
            W2t[((size_t)(c * 64 + h)) * NV + k0 + kr] = f2bf(t[kr][h]);
        }
        return;
    }
    const int b = blk - 1024;
    if (b < 1024) {                       // data f32 -> bf16 (262144 float4)
        int i = b * 256 + tid;
        float4 v = reinterpret_cast<const float4*>(data)[i];
        ushort4 o = make_ushort4(f2bf(v.x), f2bf(v.y), f2bf(v.z), f2bf(v.w));
        reinterpret_cast<ushort4*>(dataB)[i] = o;
    } else if (b < 1088) {                // out0 = adj (16384 float4)
        int i = (b - 1024) * 256 + tid;
        reinterpret_cast<float4*>(out0)[i] = reinterpret_cast<const float4*>(adj)[i];
    } else if (b < 1152) {                // g2[j]=2*neurons[h,c]*w_out[j]; BO[c]=b_out[c]+sum_h g
        int j = (b - 1088) * 256 + tid;
        int c = j >> 6, h = j & 63;
        float gv = neurons[h * NV + c] * w_out[j];
        g2[j] = 2.0f * gv;
        float s = gv;
        s += __shfl_xor(s, 1);  s += __shfl_xor(s, 2);  s += __shfl_xor(s, 4);
        s += __shfl_xor(s, 8);  s += __shfl_xor(s, 16); s += __shfl_xor(s, 32);
        if ((tid & 63) == 0) BO[c] = b_out[c] + s;
    } else {                              // bi2 = K2 * b_in (4096 float4)
        int i = (b - 1152) * 256 + tid;
        float4 v = reinterpret_cast<const float4*>(b_in)[i];
        v.x *= K2F; v.y *= K2F; v.z *= K2F; v.w *= K2F;
        reinterpret_cast<float4*>(bi2)[i] = v;
    }
}

// ---- main: PERSISTENT-N + 32x32x16 MFMA.
// 512 blocks = 32 m-strips x 16 n-chunks; each block: 8 n-tiles x 4 kt = 32
// warm pipelined K-steps (drains amortized 8x). Block 4 waves (2m x 2n),
// step-tile 128m x 128n, wave 64x64 via mfma_f32_32x32x16 (mi2 x ni2):
// halves DS bytes/FLOP vs 16x16 AND +15% MFMA rate. Ring-2 LDS 2x(A16K|B16K)
// = 64KB -> 2 blocks/CU. 1-ahead staging, counted vmcnt(8), 2 barriers/step.
// Swapped MFMA: D rows = h, D cols = m. XOR-swizzled 128B rows (R8-proven,
// 0 conflicts; rule #21 inverse-swizzle on global source).
__global__ __launch_bounds__(256, 2) void k_gemm_fused(
        const unsigned short* __restrict__ dataB,   // [4096][256] bf16
        const unsigned short* __restrict__ W2t,     // [16384][256] bf16
        const float* __restrict__ g2,               // [16384] 2*g
        const float* __restrict__ bi2,              // [16384] K2*b_in
        const float* __restrict__ BO,               // [256]  b_out + sum_h g
        float* __restrict__ out1)                   // [4096][256]
{
    __shared__ __align__(16) char lds[65536];       // 2 x (A 16K | B 16K)
    const int tid  = threadIdx.x;
    const int w    = tid >> 6;
    const int lane = tid & 63;
    const int l31  = lane & 31;
    const int hi   = lane >> 5;                     // k-octet / h-half select
    const int wm   = w & 1, wn = w >> 1;

    // 512 = 8 XCD x 2 nchunk x 32 mstrip: per XCD B-slice 2048 cols (1MB) +
    // full A (2MB) -> L2-resident.
    const int bid    = (int)blockIdx.x;
    const int nchunk = (bid & 7) * 2 + ((bid >> 3) & 1);   // 0..15
    const int mstrip = bid >> 4;                            // 0..31
    const int m0     = mstrip * 128;

    f16v acc[2][2];
#pragma unroll
    for (int mi = 0; mi < 2; ++mi)
#pragma unroll
        for (int ni = 0; ni < 2; ++ni)
            acc[mi][ni] = (f16v)(0.0f);

    // Staging geometry (R8-proven form): per stage 16KB A + 16KB B, 128B rows,
    // XOR swizzle applied to GLOBAL source, linear LDS dest, re-XOR on ds_read.
    // Thread t, load l: dest = l*4096 + t*16; row = dest>>7; inner swizzled.
    const char* dA = (const char*)dataB;
    const char* dB = (const char*)W2t;
    unsigned rowL[4], innL[4];
#pragma unroll
    for (int l = 0; l < 4; ++l) {
        int o = l * 4096 + tid * 16;
        rowL[l] = (unsigned)(o >> 7);
        innL[l] = (unsigned)((o & 127) ^ (((o >> 7) & 7) << 4));
    }
    const unsigned t16 = (unsigned)tid * 16;

    // STAGE(kt, nb, bufbase): A rows m0+row, bytes kt*128+inn; B rows nb+row.
#define STAGE(KT, NB, BUFO)                                                    \
    do {                                                                       \
        _Pragma("unroll")                                                      \
        for (int l = 0; l < 4; ++l)                                            \
            gload16(dA + (size_t)(m0 + rowL[l]) * 512 + (KT) * 128 + innL[l],  \
                    lds + (BUFO) + l * 4096 + t16);                            \
        _Pragma("unroll")                                                      \
        for (int l = 0; l < 4; ++l)                                            \
            gload16(dB + (size_t)((NB) + rowL[l]) * 512 + (KT) * 128 + innL[l],\
                    lds + (BUFO) + 16384 + l * 4096 + t16);                    \
    } while (0)

    // Prologue: stage step0 (nt=0, kt=0) into buf0.
    STAGE(0, nchunk * 1024, 0);

    for (int nt = 0; nt < 8; ++nt) {
        const int ntile = nchunk * 8 + nt;
        const int nb    = ntile * 128;              // B row base this n-tile
        const int nbN   = nb + 128;                 // next n-tile's base

#pragma unroll
        for (int kt = 0; kt < 4; ++kt) {
            const int bufo = (kt & 1) << 15;        // 0 / 32768
            // stage step s+1 (1-ahead) into the other buffer
            if (kt < 3)            STAGE(kt + 1, nb, bufo ^ 32768);
            else if (nt < 7)       STAGE(0, nbN, bufo ^ 32768);
            __builtin_amdgcn_sched_barrier(0);
            if (kt == 3 && nt == 7) { asm volatile("s_waitcnt vmcnt(0)" ::: "memory"); }
            else                    { asm volatile("s_waitcnt vmcnt(8)" ::: "memory"); }
            __builtin_amdgcn_sched_barrier(0);
            __builtin_amdgcn_s_barrier();           // step's tiles visible
            __builtin_amdgcn_sched_barrier(0);

#pragma unroll
            for (int kk = 0; kk < 4; ++kk) {        // K=64 -> 4 x k16
                const int inB = kk * 32 + hi * 16;  // byte offset within 128B row
                s8v afr[2], bfr[2];
#pragma unroll
                for (int mi = 0; mi < 2; ++mi) {
                    int ml = wm * 64 + mi * 32 + l31;
                    afr[mi] = *reinterpret_cast<const s8v*>(
                        lds + bufo + ml * 128 + (inB ^ ((ml & 7) << 4)));
                }
#pragma unroll
                for (int ni = 0; ni < 2; ++ni) {
                    int nl = wn * 64 + ni * 32 + l31;
                    bfr[ni] = *reinterpret_cast<const s8v*>(
                        lds + bufo + 16384 + nl * 128 + (inB ^ ((nl & 7) << 4)));
                }
                __builtin_amdgcn_s_setprio(1);
#pragma unroll
                for (int mi = 0; mi < 2; ++mi)
#pragma unroll
                    for (int ni = 0; ni < 2; ++ni)
                        acc[mi][ni] = __builtin_amdgcn_mfma_f32_32x32x16_bf16(
                            bfr[ni], afr[mi], acc[mi][ni], 0, 0, 0); // W first
                __builtin_amdgcn_s_setprio(0);
            }

            __builtin_amdgcn_sched_barrier(0);
            __builtin_amdgcn_s_barrier();           // reads done -> buf reusable
            __builtin_amdgcn_sched_barrier(0);
        }

        // ---- Epilogue for this n-tile (channel = ntile*2 + wn) ----
        // D layout (m74/m101): col(m) = lane&31, row(h) = (r&3)+8*(r>>2)+4*hi
        // (+ ni*32). out[m,c] = BO[c] - sum_h g2[h]*rcp(1+exp2(K2*pre+bi2[h]))
        const int cidx = ntile * 2 + wn;
        const float BOv = BO[cidx];
        float s0 = 0.f, s1 = 0.f;
#pragma unroll
        for (int ni = 0; ni < 2; ++ni) {
#pragma unroll
            for (int q = 0; q < 4; ++q) {           // q = r>>2
                int base = cidx * 64 + ni * 32 + q * 8 + hi * 4;
                float4 gq = *(const float4*)&g2 [base];
                float4 bq = *(const float4*)&bi2[base];
#pragma unroll
                for (int j = 0; j < 4; ++j) {       // r = q*4+j
                    const int r = q * 4 + j;
                    float gj = j == 0 ? gq.x : (j == 1 ? gq.y : (j == 2 ? gq.z : gq.w));
                    float bj = j == 0 ? bq.x : (j == 1 ? bq.y : (j == 2 ? bq.z : bq.w));
                    {
                        float mm = __builtin_fmaf(acc[0][ni][r], K2F, bj);
                        float e  = __builtin_amdgcn_exp2f(mm);
                        s0 = __builtin_fmaf(gj, __builtin_amdgcn_rcpf(e + 1.0f), s0);
                    }
                    {
                        float mm = __builtin_fmaf(acc[1][ni][r], K2F, bj);
                        float e  = __builtin_amdgcn_exp2f(mm);
                        s1 = __builtin_fmaf(gj, __builtin_amdgcn_rcpf(e + 1.0f), s1);
                    }
                }
            }
        }
        s0 += __shfl_xor(s0, 32);
        s1 += __shfl_xor(s1, 32);
        if (lane < 32) {
            out1[(unsigned)(m0 + wm * 64 + l31) * NV + cidx]      = BOv - s0;
            out1[(unsigned)(m0 + wm * 64 + 32 + l31) * NV + cidx] = BOv - s1;
        }
#pragma unroll
        for (int mi = 0; mi < 2; ++mi)
#pragma unroll
            for (int ni = 0; ni < 2; ++ni)
                acc[mi][ni] = (f16v)(0.0f);
    }
#undef STAGE
}

extern "C" void kernel_launch(void* const* d_in, const int* in_sizes, int n_in,
                              void* d_out, int out_size, void* d_ws, size_t ws_size,
                              hipStream_t stream) {
    const float* data    = (const float*)d_in[0];
    const float* adj     = (const float*)d_in[1];
    const float* neurons = (const float*)d_in[2];
    const float* w_in    = (const float*)d_in[3];
    const float* b_in    = (const float*)d_in[4];
    const float* w_out   = (const float*)d_in[5];
    const float* b_out   = (const float*)d_in[6];

    float* out0 = (float*)d_out;
    float* out1 = out0 + NV * NV;

    unsigned short* dataB = (unsigned short*)d_ws;                       // 2 MiB
    unsigned short* W2t   = (unsigned short*)((char*)d_ws + 2097152);    // 8 MiB
    float*          g2    = (float*)((char*)d_ws + 10485760);            // 64 KiB
    float*          bi2   = (float*)((char*)d_ws + 10551296);            // 64 KiB
    float*          BO    = (float*)((char*)d_ws + 10616832);            // 1 KiB

    hipLaunchKernelGGL(k_prep_all, dim3(2192), dim3(256), 0, stream,
                       adj, w_in, W2t, data, dataB, out0,
                       neurons, w_out, b_out, g2, BO, b_in, bi2);
    hipLaunchKernelGGL(k_gemm_fused, dim3(512), dim3(256), 0, stream,
                       dataB, W2t, g2, bi2, BO, out1);
}